// Round 9
// baseline (168.677 us; speedup 1.0000x reference)
//
#include <hip/hip_runtime.h>

// Problem constants (B=1 fixed)
#define RR     1024
#define NSEQ   128
#define CFEAT  22
#define CMSA   256
#define CPAIR  128
#define NBINS  65

typedef float f4 __attribute__((ext_vector_type(4)));
typedef float f2 __attribute__((ext_vector_type(2)));

// ---------------------------------------------------------------------------
// Kernel 1: per-residue projections + relpos table (128 blocks x 8 rows)
// ---------------------------------------------------------------------------
__global__ __launch_bounds__(256) void k_pre(
    const float* __restrict__ tf,
    const float* __restrict__ Wa, const float* __restrict__ ba,
    const float* __restrict__ Wb, const float* __restrict__ bb,
    const float* __restrict__ Wm2, const float* __restrict__ bm2,
    const float* __restrict__ Wpos, const float* __restrict__ bpos,
    float* __restrict__ a, float* __restrict__ bvp,
    float* __restrict__ tm2, float* __restrict__ pose)
{
    __shared__ float wlds[CFEAT][512];
    __shared__ float rows[8][CFEAT];
    const int t = threadIdx.x;
    const int r0 = blockIdx.x * 8;

    for (int idx = t; idx < 128 * CFEAT; idx += 256) {
        int c = idx / CFEAT, k = idx - c * CFEAT;
        wlds[k][c] = Wa[idx];
    }
    for (int idx = t; idx < 128 * CFEAT; idx += 256) {
        int c = idx / CFEAT, k = idx - c * CFEAT;
        wlds[k][128 + c] = Wb[idx];
    }
    for (int idx = t; idx < 256 * CFEAT; idx += 256) {
        int c = idx / CFEAT, k = idx - c * CFEAT;
        wlds[k][256 + c] = Wm2[idx];
    }
    for (int idx = t; idx < 8 * CFEAT; idx += 256) {
        int rr = idx / CFEAT, k = idx - rr * CFEAT;
        rows[rr][k] = tf[(r0 + rr) * CFEAT + k];
    }
    __syncthreads();

    #pragma unroll
    for (int rr = 0; rr < 8; ++rr) {
        const int r = r0 + rr;
        float s1 = 0.f, s2 = 0.f;
        #pragma unroll
        for (int k = 0; k < CFEAT; ++k) {
            float rv = rows[rr][k];
            s1 += rv * wlds[k][t];        // a (t<128) or bv (t>=128)
            s2 += rv * wlds[k][256 + t];  // tm2
        }
        tm2[r * CMSA + t] = s2 + bm2[t];
        if (t < CPAIR) a[r * CPAIR + t] = s1 + ba[t];
        else           bvp[r * CPAIR + (t - CPAIR)] = s1 + bb[t - CPAIR];
    }

    if (blockIdx.x < NBINS && t < CPAIR)
        pose[blockIdx.x * CPAIR + t] = Wpos[t * NBINS + blockIdx.x] + bpos[t];
}

// ---------------------------------------------------------------------------
// Fused kernel, 1280 blocks (5/CU, all co-resident, roles spread per-XCD):
//   pair role (1024 blocks): GLOBAL-SEQUENTIAL SWEEP of z. Chunk c = 4 KB
//       (one i, 8 j's); block pid handles chunks n*1024+pid -> the whole
//       grid writes one ~4 MB sliding window in linear address order,
//       mimicking the 6.6 TB/s fill's access pattern. NT f4 stores.
//   msa role (256 blocks): 512 consecutive pairs each (contiguous 512 KB m),
//       8 segments x 64 pairs LDS-staged, weights in registers, NT f2 stores.
// ---------------------------------------------------------------------------
__global__ __launch_bounds__(256) void k_fused(
    const int* __restrict__ resi,
    const float* __restrict__ a, const float* __restrict__ bvp,
    const float* __restrict__ pose, float* __restrict__ out_z,
    const float* __restrict__ msa,
    const float* __restrict__ Wm1, const float* __restrict__ bm1,
    const float* __restrict__ tm2, float* __restrict__ out_m)
{
    __shared__ float rows[64][24];   // msa staging, 6 KB
    const int b = blockIdx.x;
    const int t = threadIdx.x;
    const int q = b >> 3, s = b & 7;     // q: per-XCD slot, s: XCD
    const int q5 = q / 5, qm = q - q5 * 5;

    if (qm < 4) {
        // ---------------- pair role: global-sweep ----------------
        const int pid = (q5 * 4 + qm) * 8 + s;   // 0..1023
        const int c4 = (t & 31) * 4;  // channel base 0,4,...,124
        const int jo = t >> 5;        // 0..7

        #pragma unroll 2
        for (int n = 0; n < 128; ++n) {
            const int chunk = n * 1024 + pid;    // linear 4 KB chunk of z
            const int i = chunk >> 7;            // 128 chunks per i-row
            const int j = ((chunk & 127) << 3) + jo;
            int d = resi[j] - resi[i] + (NBINS / 2);
            d = min(max(d, 0), NBINS - 1);
            const f4 bvv = *(const f4*)(bvp + (long)i * CPAIR + c4);
            const f4 av  = *(const f4*)(a + (long)j * CPAIR + c4);
            const f4 pv  = *(const f4*)(pose + (long)d * CPAIR + c4);
            f4 o = av + bvv + pv;
            __builtin_nontemporal_store(
                o, (f4*)(out_z + ((long)i * RR + j) * CPAIR + c4));
        }
    } else {
        // ---------------- msa role: 512 consecutive pairs ----------------
        const int mid = q5 * 8 + s;              // 0..255
        const int c2 = (t & 127) * 2;            // channels c2, c2+1
        const int ps = t >> 7;                   // pair slot parity 0/1
        float wA[24], wB[24];
        const float* wp = Wm1 + (long)c2 * CFEAT;
        #pragma unroll
        for (int k = 0; k < CFEAT; ++k) { wA[k] = wp[k]; wB[k] = wp[CFEAT + k]; }
        wA[22] = wA[23] = wB[22] = wB[23] = 0.f;
        const float b0 = bm1[c2], b1 = bm1[c2 + 1];

        for (int seg = 0; seg < 8; ++seg) {
            const long pbase = (long)mid * 512 + seg * 64;
            __syncthreads();
            const float* src = msa + pbase * CFEAT;
            for (int idx = t; idx < 64 * CFEAT; idx += 256) {
                int p = idx / CFEAT, k = idx - p * CFEAT;
                rows[p][k] = src[idx];
            }
            if (t < 64) { rows[t][22] = 0.f; rows[t][23] = 0.f; }
            __syncthreads();

            for (int it = 0; it < 32; ++it) {
                const int p = it * 2 + ps;            // half-block-uniform
                const long pair = pbase + p;
                const int r = (int)(pair & (RR - 1)); // pair % 1024
                float a0 = 0.f, a1 = 0.f;
                #pragma unroll
                for (int k4 = 0; k4 < 6; ++k4) {
                    f4 mv = *(const f4*)&rows[p][k4 * 4];  // broadcast b128
                    a0 += mv.x * wA[k4 * 4 + 0]; a1 += mv.x * wB[k4 * 4 + 0];
                    a0 += mv.y * wA[k4 * 4 + 1]; a1 += mv.y * wB[k4 * 4 + 1];
                    a0 += mv.z * wA[k4 * 4 + 2]; a1 += mv.z * wB[k4 * 4 + 2];
                    a0 += mv.w * wA[k4 * 4 + 3]; a1 += mv.w * wB[k4 * 4 + 3];
                }
                const f2 t2 = *(const f2*)(tm2 + (long)r * CMSA + c2);
                f2 o;
                o.x = a0 + b0 + t2.x;
                o.y = a1 + b1 + t2.y;
                __builtin_nontemporal_store(o, (f2*)(out_m + pair * CMSA + c2));
            }
        }
    }
}

// ---------------------------------------------------------------------------
extern "C" void kernel_launch(void* const* d_in, const int* in_sizes, int n_in,
                              void* d_out, int out_size, void* d_ws, size_t ws_size,
                              hipStream_t stream) {
    const float* tf   = (const float*)d_in[0];
    const int*   resi = (const int*)  d_in[1];
    const float* msa  = (const float*)d_in[2];
    const float* Wa   = (const float*)d_in[3];
    const float* ba   = (const float*)d_in[4];
    const float* Wb   = (const float*)d_in[5];
    const float* bb   = (const float*)d_in[6];
    const float* Wm1  = (const float*)d_in[7];
    const float* bm1  = (const float*)d_in[8];
    const float* Wm2  = (const float*)d_in[9];
    const float* bm2  = (const float*)d_in[10];
    const float* Wpos = (const float*)d_in[11];
    const float* bpos = (const float*)d_in[12];

    float* out_m = (float*)d_out;                        // 128*1024*256
    float* out_z = out_m + (long)NSEQ * RR * CMSA;       // 1024*1024*128

    // workspace layout (floats): a | bv | tm2 | pose  (~2.13 MB total)
    float* a    = (float*)d_ws;
    float* bvp  = a   + (long)RR * CPAIR;
    float* tm2  = bvp + (long)RR * CPAIR;
    float* pose = tm2 + (long)RR * CMSA;

    k_pre<<<128, 256, 0, stream>>>(tf, Wa, ba, Wb, bb, Wm2, bm2, Wpos, bpos,
                                   a, bvp, tm2, pose);
    // 1280 blocks: 1024 pair-sweep + 256 msa, interleaved per-XCD (q%5).
    k_fused<<<1280, 256, 0, stream>>>(resi, a, bvp, pose, out_z,
                                      msa, Wm1, bm1, tm2, out_m);
}

// Round 10
// 147.384 us; speedup vs baseline: 1.1445x; 1.1445x over previous
//
#include <hip/hip_runtime.h>

// Problem constants (B=1 fixed)
#define RR     1024
#define NSEQ   128
#define CFEAT  22
#define CMSA   256
#define CPAIR  128
#define NBINS  65

typedef float f4 __attribute__((ext_vector_type(4)));

// ---------------------------------------------------------------------------
// FINAL FORM (= R3, best measured: 147.7 us).
// Optimization ledger (all single-variable A/B on MI355X):
//   - NT stores mandatory: plain = +29 us (L2 write-allocate path, NOT read
//     eviction -- R6 falsified that); sc1 = +7 us. nt < sc1 < plain.
//   - Role-split fusion (z-blocks + m-blocks in one kernel, 8-block groups)
//     beats 3-launch by ~10 us and cooperative single-launch by ~125 us.
//   - Occupancy 16 vs 32 waves/CU: null. Read staging LDS vs L2: null.
//   - Global-sequential write sweep: +20 us (worse than per-block streams).
// Ceiling: 671 MB compulsory writes / ~4.95 TB/s mixed-NT-stream ~= 136 us
// + ~10 us fixed (k_pre + boundary + ramp/tail) = the measured 148.
// ---------------------------------------------------------------------------

// ---------------------------------------------------------------------------
// Kernel 1: per-residue projections + relpos table (128 blocks x 8 rows)
//   a[r,c]   = tf[r,:] @ Wa[c,:] + ba[c]          (1024 x 128)
//   bv[r,c]  = tf[r,:] @ Wb[c,:] + bb[c]          (1024 x 128)
//   tm2[r,c] = tf[r,:] @ Wm2[c,:] + bm2[c]        (1024 x 256)
//   pose[bin,c] = Wpos[c,bin] + bpos[c]           (65 x 128)
// ---------------------------------------------------------------------------
__global__ __launch_bounds__(256) void k_pre(
    const float* __restrict__ tf,
    const float* __restrict__ Wa, const float* __restrict__ ba,
    const float* __restrict__ Wb, const float* __restrict__ bb,
    const float* __restrict__ Wm2, const float* __restrict__ bm2,
    const float* __restrict__ Wpos, const float* __restrict__ bpos,
    float* __restrict__ a, float* __restrict__ bvp,
    float* __restrict__ tm2, float* __restrict__ pose)
{
    __shared__ float wlds[CFEAT][512];
    __shared__ float rows[8][CFEAT];
    const int t = threadIdx.x;
    const int r0 = blockIdx.x * 8;

    for (int idx = t; idx < 128 * CFEAT; idx += 256) {
        int c = idx / CFEAT, k = idx - c * CFEAT;
        wlds[k][c] = Wa[idx];
    }
    for (int idx = t; idx < 128 * CFEAT; idx += 256) {
        int c = idx / CFEAT, k = idx - c * CFEAT;
        wlds[k][128 + c] = Wb[idx];
    }
    for (int idx = t; idx < 256 * CFEAT; idx += 256) {
        int c = idx / CFEAT, k = idx - c * CFEAT;
        wlds[k][256 + c] = Wm2[idx];
    }
    for (int idx = t; idx < 8 * CFEAT; idx += 256) {
        int rr = idx / CFEAT, k = idx - rr * CFEAT;
        rows[rr][k] = tf[(r0 + rr) * CFEAT + k];
    }
    __syncthreads();

    #pragma unroll
    for (int rr = 0; rr < 8; ++rr) {
        const int r = r0 + rr;
        float s1 = 0.f, s2 = 0.f;
        #pragma unroll
        for (int k = 0; k < CFEAT; ++k) {
            float rv = rows[rr][k];
            s1 += rv * wlds[k][t];        // a (t<128) or bv (t>=128)
            s2 += rv * wlds[k][256 + t];  // tm2
        }
        tm2[r * CMSA + t] = s2 + bm2[t];
        if (t < CPAIR) a[r * CPAIR + t] = s1 + ba[t];
        else           bvp[r * CPAIR + (t - CPAIR)] = s1 + bb[t - CPAIR];
    }

    if (blockIdx.x < NBINS && t < CPAIR)
        pose[blockIdx.x * CPAIR + t] = Wpos[t * NBINS + blockIdx.x] + bpos[t];
}

// ---------------------------------------------------------------------------
// Fused kernel: block-role split (per 8-block group, so role parity does not
// correlate with XCD round-robin parity).
//   pair role (2048 blocks): z[i,j,c] = a[j,c] + bv[i,c] + pose[bin][c],
//                            each block = half a row (512 j), pose via L1/L2.
//   msa role  (2048 blocks): m[n,r,c] = msa[n,r,:]@Wm1.T + bm1 + tm2[r,:],
//                            weights in registers, rows in LDS.
// ---------------------------------------------------------------------------
#define PPB 64  // (n,r) pairs per msa block

__global__ __launch_bounds__(256) void k_fused(
    const int* __restrict__ resi,
    const float* __restrict__ a, const float* __restrict__ bvp,
    const float* __restrict__ pose, float* __restrict__ out_z,
    const float* __restrict__ msa,
    const float* __restrict__ Wm1, const float* __restrict__ bm1,
    const float* __restrict__ tm2, float* __restrict__ out_m)
{
    __shared__ union U {
        struct { float wt[CFEAT][CMSA]; float rows[PPB][24]; } m;  // 28.7 KB
        struct { int rj[512]; } p;                                 // 2 KB
    } sm;
    const int bx = blockIdx.x;
    const int grp = bx >> 3, sub = bx & 7;
    const int id = (grp >> 1) * 8 + sub;   // role-local block id, 0..2047
    const int t = threadIdx.x;

    if ((grp & 1) == 0) {
        // ---------------- pair role ----------------
        const int i = id >> 1;                 // row 0..1023
        const int jbase = (id & 1) * 512;      // half-row
        for (int idx = t; idx < 512; idx += 256)
            sm.p.rj[idx] = resi[jbase + idx];
        __syncthreads();

        const int c4 = (t & 31) * 4;  // channel base 0,4,...,124
        const int jo = t >> 5;        // 0..7
        const int ri = resi[i];
        const f4 bvv = *(const f4*)(bvp + (long)i * CPAIR + c4);
        float* dst = out_z + ((long)i * RR + jbase) * CPAIR;

        #pragma unroll 4
        for (int jj = 0; jj < 512; jj += 8) {
            const int jl = jj + jo;
            int d = sm.p.rj[jl] - ri + (NBINS / 2);
            d = min(max(d, 0), NBINS - 1);
            const f4 av = *(const f4*)(a + (long)(jbase + jl) * CPAIR + c4);
            const f4 pv = *(const f4*)(pose + (long)d * CPAIR + c4);
            f4 o = av + bvv + pv;
            __builtin_nontemporal_store(o, (f4*)(dst + (long)jl * CPAIR + c4));
        }
    } else {
        // ---------------- msa role ----------------
        for (int idx = t; idx < CMSA * CFEAT; idx += 256) {
            int c = idx / CFEAT, k = idx - c * CFEAT;
            sm.m.wt[k][c] = Wm1[idx];
        }
        const long pbase = (long)id * PPB;
        const float* src = msa + pbase * CFEAT;
        for (int idx = t; idx < PPB * CFEAT; idx += 256) {
            int p = idx / CFEAT, k = idx - p * CFEAT;
            sm.m.rows[p][k] = src[idx];
        }
        if (t < PPB) { sm.m.rows[t][22] = 0.f; sm.m.rows[t][23] = 0.f; }
        __syncthreads();

        const int c  = (t & 63) * 4;  // 4 output channels
        const int wv = t >> 6;        // wave id 0..3

        f4 wr[24];
        #pragma unroll
        for (int k = 0; k < CFEAT; ++k) wr[k] = *(const f4*)&sm.m.wt[k][c];
        wr[22] = (f4){0.f, 0.f, 0.f, 0.f};
        wr[23] = (f4){0.f, 0.f, 0.f, 0.f};
        const f4 b4 = *(const f4*)(bm1 + c);

        for (int it = 0; it < PPB / 4; ++it) {
            const int p = it * 4 + wv;            // wave-uniform pair slot
            const long pair = pbase + p;
            const int r = (int)(pair & (RR - 1)); // pair % 1024
            f4 acc = (f4){0.f, 0.f, 0.f, 0.f};
            #pragma unroll
            for (int k4 = 0; k4 < 6; ++k4) {
                f4 mv = *(const f4*)&sm.m.rows[p][k4 * 4];  // broadcast b128
                acc += mv.x * wr[k4 * 4 + 0];
                acc += mv.y * wr[k4 * 4 + 1];
                acc += mv.z * wr[k4 * 4 + 2];
                acc += mv.w * wr[k4 * 4 + 3];
            }
            const f4 t4 = *(const f4*)(tm2 + (long)r * CMSA + c);
            f4 o = acc + b4 + t4;
            __builtin_nontemporal_store(o, (f4*)(out_m + pair * CMSA + c));
        }
    }
}

// ---------------------------------------------------------------------------
extern "C" void kernel_launch(void* const* d_in, const int* in_sizes, int n_in,
                              void* d_out, int out_size, void* d_ws, size_t ws_size,
                              hipStream_t stream) {
    const float* tf   = (const float*)d_in[0];
    const int*   resi = (const int*)  d_in[1];
    const float* msa  = (const float*)d_in[2];
    const float* Wa   = (const float*)d_in[3];
    const float* ba   = (const float*)d_in[4];
    const float* Wb   = (const float*)d_in[5];
    const float* bb   = (const float*)d_in[6];
    const float* Wm1  = (const float*)d_in[7];
    const float* bm1  = (const float*)d_in[8];
    const float* Wm2  = (const float*)d_in[9];
    const float* bm2  = (const float*)d_in[10];
    const float* Wpos = (const float*)d_in[11];
    const float* bpos = (const float*)d_in[12];

    float* out_m = (float*)d_out;                        // 128*1024*256
    float* out_z = out_m + (long)NSEQ * RR * CMSA;       // 1024*1024*128

    // workspace layout (floats): a | bv | tm2 | pose  (~2.13 MB total)
    float* a    = (float*)d_ws;
    float* bvp  = a   + (long)RR * CPAIR;
    float* tm2  = bvp + (long)RR * CPAIR;
    float* pose = tm2 + (long)RR * CMSA;

    k_pre<<<128, 256, 0, stream>>>(tf, Wa, ba, Wb, bb, Wm2, bm2, Wpos, bpos,
                                   a, bvp, tm2, pose);
    // 4096 blocks: 2048 pair-role + 2048 msa-role, interleaved in 8-block
    // groups so each XCD gets an even mix of both roles.
    k_fused<<<4096, 256, 0, stream>>>(resi, a, bvp, pose, out_z,
                                      msa, Wm1, bm1, tm2, out_m);
}